// Round 1
// baseline (193.791 us; speedup 1.0000x reference)
//
#include <hip/hip_runtime.h>
#include <hip/hip_bf16.h>

typedef __attribute__((ext_vector_type(4))) float f32x4;
typedef __attribute__((ext_vector_type(8))) short bf16x8;
typedef __attribute__((ext_vector_type(4))) short bf16x4;

constexpr int SEQ   = 2048;
constexpr int DH    = 64;
constexpr int QBLK  = 64;
constexpr int KVBLK = 64;
constexpr int NQT   = SEQ / QBLK;   // 32
constexpr int BH    = 64;           // 4*16

__device__ __forceinline__ short f2bf(float f) {
    union { float f; unsigned u; } x; x.f = f;
    unsigned r = x.u + 0x7fffu + ((x.u >> 16) & 1u);   // RNE
    return (short)(r >> 16);
}

__global__ __launch_bounds__(256) void fattn_kernel(
    const float* __restrict__ Qg, const float* __restrict__ Kg,
    const float* __restrict__ Vg, float* __restrict__ Og)
{
    __shared__ short sK[KVBLK * DH];      // [kv][d], rows 128B, XOR-swizzled
    __shared__ short sVt[DH * KVBLK];     // [d][kv], rows 128B, XOR-swizzled
    __shared__ short sP[4][16 * DH];      // per-wave P tile 16x64

    const int bid = blockIdx.x;
    const int bh  = bid & (BH - 1);
    int qt = bid >> 6;
    qt = NQT - 1 - qt;                    // heavy q-tiles dispatch first
    const int q0 = qt * QBLK;

    const int tid  = threadIdx.x;
    const int wid  = tid >> 6;
    const int lane = tid & 63;
    const int lg   = lane >> 4;
    const int l15  = lane & 15;

    const size_t base = (size_t)bh * SEQ * DH;
    const float* Qb = Qg + base;
    const float* Kb = Kg + base;
    const float* Vb = Vg + base;

    // ---- Q fragments (A operand), scale 0.125 folded in ----
    const int qrow = q0 + wid * 16 + l15;
    bf16x8 qf[2];
    {
        const float* qp = Qb + (size_t)qrow * DH + lg * 8;
        #pragma unroll
        for (int ks = 0; ks < 2; ++ks) {
            f32x4 a = *(const f32x4*)(qp + ks * 32);
            f32x4 b = *(const f32x4*)(qp + ks * 32 + 4);
            bf16x8 f;
            #pragma unroll
            for (int j = 0; j < 4; ++j) {
                f[j]     = f2bf(a[j] * 0.125f);
                f[j + 4] = f2bf(b[j] * 0.125f);
            }
            qf[ks] = f;
        }
    }

    f32x4 o[4];
    float m_i[4], l_i[4];
    #pragma unroll
    for (int n = 0; n < 4; ++n) o[n] = (f32x4){0.f, 0.f, 0.f, 0.f};
    #pragma unroll
    for (int r = 0; r < 4; ++r) { m_i[r] = -1e30f; l_i[r] = 0.f; }

    for (int t = 0; t <= qt; ++t) {
        const int kv0 = t * KVBLK;
        __syncthreads();   // previous tile fully consumed before overwrite

        // ---- stage K and V^T into LDS (bf16, swizzled) ----
        #pragma unroll
        for (int it = 0; it < 4; ++it) {
            const int i4 = it * 256 + tid;        // 0..1023 float4's
            const int r  = i4 >> 4;               // kv row 0..63
            const int c4 = (i4 & 15) << 2;        // d base 0..60
            const size_t gidx = (size_t)(kv0 + r) * DH + c4;
            f32x4 kx = *(const f32x4*)(Kb + gidx);
            bf16x4 kb;
            #pragma unroll
            for (int j = 0; j < 4; ++j) kb[j] = f2bf(kx[j]);
            *(bf16x4*)((char*)sK + r * 128 + ((c4 * 2) ^ ((r & 7) << 4))) = kb;

            f32x4 vx = *(const f32x4*)(Vb + gidx);
            #pragma unroll
            for (int j = 0; j < 4; ++j) {
                const int d = c4 + j;
                *(short*)((char*)sVt + d * 128 + ((r * 2) ^ ((d & 7) << 4))) = f2bf(vx[j]);
            }
        }
        __syncthreads();

        // ---- S = Q K^T (scaled) ----
        f32x4 s[4];
        #pragma unroll
        for (int n = 0; n < 4; ++n) s[n] = (f32x4){0.f, 0.f, 0.f, 0.f};
        #pragma unroll
        for (int ks = 0; ks < 2; ++ks) {
            const int dby = (ks * 32 + lg * 8) * 2;
            #pragma unroll
            for (int n = 0; n < 4; ++n) {
                const int kvr = n * 16 + l15;
                bf16x8 kf = *(const bf16x8*)((const char*)sK + kvr * 128 + (dby ^ ((kvr & 7) << 4)));
                s[n] = __builtin_amdgcn_mfma_f32_16x16x32_bf16(qf[ks], kf, s[n], 0, 0, 0);
            }
        }

        // ---- causal mask (diagonal tile only) ----
        if (t == qt) {
            const int row0 = q0 + wid * 16 + lg * 4;
            #pragma unroll
            for (int n = 0; n < 4; ++n) {
                const int col = kv0 + n * 16 + l15;
                #pragma unroll
                for (int r = 0; r < 4; ++r)
                    if (col > row0 + r) s[n][r] = -1e30f;
            }
        }

        // ---- online softmax ----
        float pmax[4];
        #pragma unroll
        for (int r = 0; r < 4; ++r)
            pmax[r] = fmaxf(fmaxf(s[0][r], s[1][r]), fmaxf(s[2][r], s[3][r]));
        #pragma unroll
        for (int r = 0; r < 4; ++r) {
            pmax[r] = fmaxf(pmax[r], __shfl_xor(pmax[r], 1));
            pmax[r] = fmaxf(pmax[r], __shfl_xor(pmax[r], 2));
            pmax[r] = fmaxf(pmax[r], __shfl_xor(pmax[r], 4));
            pmax[r] = fmaxf(pmax[r], __shfl_xor(pmax[r], 8));
        }
        float cf[4];
        #pragma unroll
        for (int r = 0; r < 4; ++r) {
            const float mn = fmaxf(m_i[r], pmax[r]);
            cf[r] = __expf(m_i[r] - mn);
            m_i[r] = mn;
        }
        float rs[4] = {0.f, 0.f, 0.f, 0.f};
        #pragma unroll
        for (int n = 0; n < 4; ++n)
            #pragma unroll
            for (int r = 0; r < 4; ++r) {
                const float p = __expf(s[n][r] - m_i[r]);
                s[n][r] = p;
                rs[r] += p;
            }
        #pragma unroll
        for (int r = 0; r < 4; ++r) {
            rs[r] += __shfl_xor(rs[r], 1);
            rs[r] += __shfl_xor(rs[r], 2);
            rs[r] += __shfl_xor(rs[r], 4);
            rs[r] += __shfl_xor(rs[r], 8);
            l_i[r] = l_i[r] * cf[r] + rs[r];
        }
        #pragma unroll
        for (int n = 0; n < 4; ++n)
            #pragma unroll
            for (int r = 0; r < 4; ++r) o[n][r] *= cf[r];

        // ---- P -> LDS (C-layout write, swizzled) ----
        short* Pw = &sP[wid][0];
        #pragma unroll
        for (int n = 0; n < 4; ++n)
            #pragma unroll
            for (int r = 0; r < 4; ++r) {
                const int row = lg * 4 + r;
                const int col = n * 16 + l15;
                *(short*)((char*)Pw + row * 128 + ((col * 2) ^ ((row & 7) << 4))) = f2bf(s[n][r]);
            }
        asm volatile("s_waitcnt lgkmcnt(0)" ::: "memory");

        // ---- O += P V ----
        #pragma unroll
        for (int ks = 0; ks < 2; ++ks) {
            const int kby = (ks * 32 + lg * 8) * 2;
            bf16x8 pf = *(const bf16x8*)((const char*)Pw + l15 * 128 + (kby ^ ((l15 & 7) << 4)));
            #pragma unroll
            for (int n = 0; n < 4; ++n) {
                const int d = n * 16 + l15;
                bf16x8 vf = *(const bf16x8*)((const char*)sVt + d * 128 + (kby ^ ((d & 7) << 4)));
                o[n] = __builtin_amdgcn_mfma_f32_16x16x32_bf16(pf, vf, o[n], 0, 0, 0);
            }
        }
    }

    // ---- epilogue: O / l ----
    float inv[4];
    #pragma unroll
    for (int r = 0; r < 4; ++r) inv[r] = 1.0f / l_i[r];
    float* Ob = Og + base;
    #pragma unroll
    for (int n = 0; n < 4; ++n)
        #pragma unroll
        for (int r = 0; r < 4; ++r) {
            const int row = q0 + wid * 16 + lg * 4 + r;
            Ob[(size_t)row * DH + n * 16 + l15] = o[n][r] * inv[r];
        }
}

extern "C" void kernel_launch(void* const* d_in, const int* in_sizes, int n_in,
                              void* d_out, int out_size, void* d_ws, size_t ws_size,
                              hipStream_t stream) {
    const float* q = (const float*)d_in[0];
    const float* k = (const float*)d_in[1];
    const float* v = (const float*)d_in[2];
    // d_in[3] is the causal tril mask — structure known, not read.
    float* out = (float*)d_out;
    dim3 grid(BH * NQT);   // 2048
    dim3 block(256);
    fattn_kernel<<<grid, block, 0, stream>>>(q, k, v, out);
}

// Round 2
// 155.467 us; speedup vs baseline: 1.2465x; 1.2465x over previous
//
#include <hip/hip_runtime.h>
#include <hip/hip_bf16.h>

typedef __attribute__((ext_vector_type(4))) float f32x4;
typedef __attribute__((ext_vector_type(8))) short bf16x8;
typedef __attribute__((ext_vector_type(4))) short bf16x4;

constexpr int SEQ   = 2048;
constexpr int DH    = 64;
constexpr int QBLK  = 64;
constexpr int KVBLK = 64;
constexpr int NQT   = SEQ / QBLK;   // 32
constexpr int BH    = 64;           // 4*16

__device__ __forceinline__ short f2bf(float f) {
    union { float f; unsigned u; } x; x.f = f;
    unsigned r = x.u + 0x7fffu + ((x.u >> 16) & 1u);   // RNE
    return (short)(r >> 16);
}

// ---- prep: K -> bf16 [bh][s][d]; V -> bf16 transposed [bh][d][s] ----
__global__ __launch_bounds__(256) void prep_kernel(
    const float* __restrict__ Kg, const float* __restrict__ Vg,
    short* __restrict__ Kb, short* __restrict__ Vt)
{
    __shared__ short sT[64][66];          // +2 pad: breaks 16-row bank wrap
    const int bid = blockIdx.x;
    const int bh  = bid & (BH - 1);
    const int st  = bid >> 6;
    const int s0  = st * 64;
    const size_t base = (size_t)bh * SEQ * DH;
    const int tid = threadIdx.x;

    #pragma unroll
    for (int it = 0; it < 4; ++it) {
        const int i4 = it * 256 + tid;        // 0..1023 float4s
        const int r  = i4 >> 4;               // row 0..63
        const int c4 = (i4 & 15) << 2;        // col base
        const size_t gidx = base + (size_t)(s0 + r) * DH + c4;
        f32x4 kx = *(const f32x4*)(Kg + gidx);
        bf16x4 kb4;
        #pragma unroll
        for (int j = 0; j < 4; ++j) kb4[j] = f2bf(kx[j]);
        *(bf16x4*)(Kb + gidx) = kb4;
        f32x4 vx = *(const f32x4*)(Vg + gidx);
        #pragma unroll
        for (int j = 0; j < 4; ++j) sT[r][c4 + j] = f2bf(vx[j]);
    }
    __syncthreads();

    // transposed write-out: thread -> (d = tid>>2, 16 consecutive s)
    const int d   = tid >> 2;
    const int seg = (tid & 3) * 16;
    bf16x8 lo, hi;
    #pragma unroll
    for (int m = 0; m < 8; ++m) { lo[m] = sT[seg + m][d]; hi[m] = sT[seg + 8 + m][d]; }
    short* Vo = Vt + base + (size_t)d * SEQ + (s0 + seg);
    *(bf16x8*)Vo       = lo;
    *(bf16x8*)(Vo + 8) = hi;
}

__global__ __launch_bounds__(256) void fattn_kernel(
    const float* __restrict__ Qg, const short* __restrict__ Kb,
    const short* __restrict__ Vt, float* __restrict__ Og)
{
    __shared__ short sK[KVBLK * DH];      // [kv][d], rows 128B, XOR-swizzled
    __shared__ short sVt[DH * KVBLK];     // [d][kv], rows 128B, XOR-swizzled
    __shared__ short sP[4][16 * DH];      // per-wave P tile 16x64

    const int bid = blockIdx.x;
    const int bh  = bid & (BH - 1);
    int qt = bid >> 6;
    qt = NQT - 1 - qt;                    // heavy q-tiles dispatch first
    const int q0 = qt * QBLK;

    const int tid  = threadIdx.x;
    const int wid  = tid >> 6;
    const int lane = tid & 63;
    const int lg   = lane >> 4;
    const int l15  = lane & 15;

    const size_t base = (size_t)bh * SEQ * DH;
    const float* Qb = Qg + base;
    const short* Kbp = Kb + base;
    const short* Vtp = Vt + base;

    // ---- Q fragments (A operand), scale 0.125 folded in ----
    const int qrow = q0 + wid * 16 + l15;
    bf16x8 qf[2];
    {
        const float* qp = Qb + (size_t)qrow * DH + lg * 8;
        #pragma unroll
        for (int ks = 0; ks < 2; ++ks) {
            f32x4 a = *(const f32x4*)(qp + ks * 32);
            f32x4 b = *(const f32x4*)(qp + ks * 32 + 4);
            bf16x8 f;
            #pragma unroll
            for (int j = 0; j < 4; ++j) {
                f[j]     = f2bf(a[j] * 0.125f);
                f[j + 4] = f2bf(b[j] * 0.125f);
            }
            qf[ks] = f;
        }
    }

    f32x4 o[4];
    float m_i[4], l_i[4];
    #pragma unroll
    for (int n = 0; n < 4; ++n) o[n] = (f32x4){0.f, 0.f, 0.f, 0.f};
    #pragma unroll
    for (int r = 0; r < 4; ++r) { m_i[r] = -1e30f; l_i[r] = 0.f; }

    for (int t = 0; t <= qt; ++t) {
        const int kv0 = t * KVBLK;
        __syncthreads();   // previous tile fully consumed before overwrite

        // ---- stage K and V^T tiles (bf16 in global, vectorized, swizzled) ----
        #pragma unroll
        for (int it = 0; it < 2; ++it) {
            const int i16 = it * 256 + tid;       // 0..511 16B-chunks
            const int r   = i16 >> 3;             // row 0..63
            const int cb  = (i16 & 7) * 16;       // byte col 0..112
            bf16x8 kx = *(const bf16x8*)((const char*)(Kbp + (size_t)(kv0 + r) * DH) + cb);
            *(bf16x8*)((char*)sK + r * 128 + (cb ^ ((r & 7) << 4))) = kx;
            bf16x8 vx = *(const bf16x8*)((const char*)(Vtp + (size_t)r * SEQ + kv0) + cb);
            *(bf16x8*)((char*)sVt + r * 128 + (cb ^ ((r & 7) << 4))) = vx;
        }
        __syncthreads();

        // ---- S = Q K^T (scaled) ----
        f32x4 s[4];
        #pragma unroll
        for (int n = 0; n < 4; ++n) s[n] = (f32x4){0.f, 0.f, 0.f, 0.f};
        #pragma unroll
        for (int ks = 0; ks < 2; ++ks) {
            const int dby = (ks * 32 + lg * 8) * 2;
            #pragma unroll
            for (int n = 0; n < 4; ++n) {
                const int kvr = n * 16 + l15;
                bf16x8 kf = *(const bf16x8*)((const char*)sK + kvr * 128 + (dby ^ ((kvr & 7) << 4)));
                s[n] = __builtin_amdgcn_mfma_f32_16x16x32_bf16(qf[ks], kf, s[n], 0, 0, 0);
            }
        }

        // ---- causal mask (diagonal tile only) ----
        if (t == qt) {
            const int row0 = q0 + wid * 16 + lg * 4;
            #pragma unroll
            for (int n = 0; n < 4; ++n) {
                const int col = kv0 + n * 16 + l15;
                #pragma unroll
                for (int r = 0; r < 4; ++r)
                    if (col > row0 + r) s[n][r] = -1e30f;
            }
        }

        // ---- online softmax ----
        float pmax[4];
        #pragma unroll
        for (int r = 0; r < 4; ++r)
            pmax[r] = fmaxf(fmaxf(s[0][r], s[1][r]), fmaxf(s[2][r], s[3][r]));
        #pragma unroll
        for (int r = 0; r < 4; ++r) {
            pmax[r] = fmaxf(pmax[r], __shfl_xor(pmax[r], 1));
            pmax[r] = fmaxf(pmax[r], __shfl_xor(pmax[r], 2));
            pmax[r] = fmaxf(pmax[r], __shfl_xor(pmax[r], 4));
            pmax[r] = fmaxf(pmax[r], __shfl_xor(pmax[r], 8));
        }
        float cf[4];
        #pragma unroll
        for (int r = 0; r < 4; ++r) {
            const float mn = fmaxf(m_i[r], pmax[r]);
            cf[r] = __expf(m_i[r] - mn);
            m_i[r] = mn;
        }
        float rs[4] = {0.f, 0.f, 0.f, 0.f};
        #pragma unroll
        for (int n = 0; n < 4; ++n)
            #pragma unroll
            for (int r = 0; r < 4; ++r) {
                const float p = __expf(s[n][r] - m_i[r]);
                s[n][r] = p;
                rs[r] += p;
            }
        #pragma unroll
        for (int r = 0; r < 4; ++r) {
            rs[r] += __shfl_xor(rs[r], 1);
            rs[r] += __shfl_xor(rs[r], 2);
            rs[r] += __shfl_xor(rs[r], 4);
            rs[r] += __shfl_xor(rs[r], 8);
            l_i[r] = l_i[r] * cf[r] + rs[r];
        }
        #pragma unroll
        for (int n = 0; n < 4; ++n)
            #pragma unroll
            for (int r = 0; r < 4; ++r) o[n][r] *= cf[r];

        // ---- P -> LDS (C-layout write, swizzled) ----
        short* Pw = &sP[wid][0];
        #pragma unroll
        for (int n = 0; n < 4; ++n)
            #pragma unroll
            for (int r = 0; r < 4; ++r) {
                const int row = lg * 4 + r;
                const int col = n * 16 + l15;
                *(short*)((char*)Pw + row * 128 + ((col * 2) ^ ((row & 7) << 4))) = f2bf(s[n][r]);
            }
        asm volatile("s_waitcnt lgkmcnt(0)" ::: "memory");

        // ---- O += P V ----
        #pragma unroll
        for (int ks = 0; ks < 2; ++ks) {
            const int kby = (ks * 32 + lg * 8) * 2;
            bf16x8 pf = *(const bf16x8*)((const char*)Pw + l15 * 128 + (kby ^ ((l15 & 7) << 4)));
            #pragma unroll
            for (int n = 0; n < 4; ++n) {
                const int d = n * 16 + l15;
                bf16x8 vf = *(const bf16x8*)((const char*)sVt + d * 128 + (kby ^ ((d & 7) << 4)));
                o[n] = __builtin_amdgcn_mfma_f32_16x16x32_bf16(pf, vf, o[n], 0, 0, 0);
            }
        }
    }

    // ---- epilogue: O / l ----
    float inv[4];
    #pragma unroll
    for (int r = 0; r < 4; ++r) inv[r] = 1.0f / l_i[r];
    float* Ob = Og + base;
    #pragma unroll
    for (int n = 0; n < 4; ++n)
        #pragma unroll
        for (int r = 0; r < 4; ++r) {
            const int row = q0 + wid * 16 + lg * 4 + r;
            Ob[(size_t)row * DH + n * 16 + l15] = o[n][r] * inv[r];
        }
}

extern "C" void kernel_launch(void* const* d_in, const int* in_sizes, int n_in,
                              void* d_out, int out_size, void* d_ws, size_t ws_size,
                              hipStream_t stream) {
    const float* q = (const float*)d_in[0];
    const float* k = (const float*)d_in[1];
    const float* v = (const float*)d_in[2];
    // d_in[3] is the causal tril mask — structure known, not read.
    float* out = (float*)d_out;

    short* Kb = (short*)d_ws;                          // 16 MiB bf16 K
    short* Vt = Kb + (size_t)BH * SEQ * DH;            // 16 MiB bf16 V^T

    dim3 block(256);
    prep_kernel<<<dim3(BH * NQT), block, 0, stream>>>(k, v, Kb, Vt);
    fattn_kernel<<<dim3(BH * NQT), block, 0, stream>>>(q, Kb, Vt, out);
}

// Round 3
// 81.485 us; speedup vs baseline: 2.3783x; 1.9079x over previous
//
#include <hip/hip_runtime.h>
#include <hip/hip_bf16.h>

typedef __attribute__((ext_vector_type(4)))  float f32x4;
typedef __attribute__((ext_vector_type(16))) float f32x16;
typedef __attribute__((ext_vector_type(8)))  short bf16x8;
typedef __attribute__((ext_vector_type(4)))  short bf16x4;

constexpr int SEQ = 2048;
constexpr int DH  = 64;
constexpr int BH  = 64;     // 4*16 heads
constexpr int QB  = 256;    // q rows per block (8 waves x 32)
constexpr int KB  = 64;     // kv rows per tile
constexpr int NQT = SEQ / QB;   // 8
constexpr int NST = SEQ / 64;   // 32 (prep tiles)

__device__ __forceinline__ short f2bf(float f) {
    union { float f; unsigned u; } x; x.f = f;
    unsigned r = x.u + 0x7fffu + ((x.u >> 16) & 1u);   // RNE
    return (short)(r >> 16);
}

__device__ __forceinline__ unsigned cvtpk(float lo, float hi) {
    unsigned r;
    asm("v_cvt_pk_bf16_f32 %0, %1, %2" : "=v"(r) : "v"(lo), "v"(hi));
    return r;
}

__device__ __forceinline__ float exp2fast(float x) {
#if __has_builtin(__builtin_amdgcn_exp2f)
    return __builtin_amdgcn_exp2f(x);
#else
    float r;
    asm("v_exp_f32 %0, %1\n\ts_nop 0" : "=v"(r) : "v"(x));  // s_nop covers trans-use hazard
    return r;
#endif
}

// halves swap: x = [a_lo, b_lo], y = [a_hi, b_hi]
__device__ __forceinline__ void half_swap(unsigned a, unsigned b, unsigned &x, unsigned &y) {
#if __has_builtin(__builtin_amdgcn_permlane32_swap)
    auto rr = __builtin_amdgcn_permlane32_swap(a, b, false, false);
    x = rr[0]; y = rr[1];
#else
    unsigned as = (unsigned)__shfl_xor((int)a, 32);
    unsigned bs = (unsigned)__shfl_xor((int)b, 32);
    const bool lo = ((threadIdx.x & 63) < 32);
    x = lo ? a : bs;
    y = lo ? as : b;
#endif
}

// ---- prep: K -> bf16 [bh][s][d]; V -> bf16 transposed [bh][d][s] ----
__global__ __launch_bounds__(256) void prep_kernel(
    const float* __restrict__ Kg, const float* __restrict__ Vg,
    short* __restrict__ Kb, short* __restrict__ Vt)
{
    __shared__ short sT[64][66];
    const int bid = blockIdx.x;
    const int bh  = bid & (BH - 1);
    const int st  = bid >> 6;
    const int s0  = st * 64;
    const size_t base = (size_t)bh * SEQ * DH;
    const int tid = threadIdx.x;

    #pragma unroll
    for (int it = 0; it < 4; ++it) {
        const int i4 = it * 256 + tid;
        const int r  = i4 >> 4;
        const int c4 = (i4 & 15) << 2;
        const size_t gidx = base + (size_t)(s0 + r) * DH + c4;
        f32x4 kx = *(const f32x4*)(Kg + gidx);
        bf16x4 kb4;
        #pragma unroll
        for (int j = 0; j < 4; ++j) kb4[j] = f2bf(kx[j]);
        *(bf16x4*)(Kb + gidx) = kb4;
        f32x4 vx = *(const f32x4*)(Vg + gidx);
        #pragma unroll
        for (int j = 0; j < 4; ++j) sT[r][c4 + j] = f2bf(vx[j]);
    }
    __syncthreads();

    const int d   = tid >> 2;
    const int seg = (tid & 3) * 16;
    bf16x8 lo, hi;
    #pragma unroll
    for (int m = 0; m < 8; ++m) { lo[m] = sT[seg + m][d]; hi[m] = sT[seg + 8 + m][d]; }
    short* Vo = Vt + base + (size_t)d * SEQ + (s0 + seg);
    *(bf16x8*)Vo       = lo;
    *(bf16x8*)(Vo + 8) = hi;
}

// ---- fused attention: swapped-QK^T 32x32 structure, in-register softmax ----
__global__ __launch_bounds__(512) void fattn2_kernel(
    const float* __restrict__ Qg, const short* __restrict__ Kb,
    const short* __restrict__ Vt, float* __restrict__ Og)
{
    __shared__ short sK[KB * DH];   // [kv][d], rows 128B, XOR-swizzled
    __shared__ short sV[DH * KB];   // [d][kv], rows 128B, XOR-swizzled

    const int bid = blockIdx.x;
    const int g   = bid >> 6;
    const int bh  = bid & 63;
    // pair heavy+light q-tiles per CU: g 0..3 -> qt 7..4, g 4..7 -> qt 0..3
    const int qt  = (g < 4) ? (7 - g) : (g - 4);
    const int q0  = qt * QB;

    const int tid  = threadIdx.x;
    const int wid  = tid >> 6;
    const int lane = tid & 63;
    const int l31  = lane & 31;
    const int hi   = lane >> 5;

    const size_t base = (size_t)bh * SEQ * DH;
    const float* Qb = Qg + base;
    const short* Kp = Kb + base;
    const short* Vp = Vt + base;

    const int qw = q0 + wid * 32;   // wave's q base
    const int qr = qw + l31;        // this lane's q row

    // Q B-fragments; scale = (1/8)*log2(e) so p = exp2(st - m) directly
    constexpr float QSCALE = 0.125f * 1.44269504088896340736f;
    bf16x8 qf[4];
    #pragma unroll
    for (int dt = 0; dt < 4; ++dt) {
        const float* qp = Qb + (size_t)qr * DH + dt * 16 + hi * 8;
        f32x4 a = *(const f32x4*)qp;
        f32x4 b = *(const f32x4*)(qp + 4);
        bf16x8 f;
        #pragma unroll
        for (int j = 0; j < 4; ++j) { f[j] = f2bf(a[j] * QSCALE); f[j + 4] = f2bf(b[j] * QSCALE); }
        qf[dt] = f;
    }

    f32x16 o0, o1;
    #pragma unroll
    for (int r = 0; r < 16; ++r) { o0[r] = 0.f; o1[r] = 0.f; }
    float m_i = -1e30f, l_i = 0.f;

    const int ntile = qt * 4 + 4;
    for (int t = 0; t < ntile; ++t) {
        const int kv0 = t * KB;
        __syncthreads();
        {   // stage K tile + V^T tile (bf16 global -> swizzled LDS), 16B per thread each
            const int r  = tid >> 3;
            const int cb = (tid & 7) * 16;
            bf16x8 kx = *(const bf16x8*)((const char*)(Kp + (size_t)(kv0 + r) * DH) + cb);
            *(bf16x8*)((char*)sK + r * 128 + (cb ^ ((r & 7) << 4))) = kx;
            bf16x8 vx = *(const bf16x8*)((const char*)(Vp + (size_t)r * SEQ + kv0) + cb);
            *(bf16x8*)((char*)sV + r * 128 + (cb ^ ((r & 7) << 4))) = vx;
        }
        __syncthreads();

        if (kv0 > qw + 31) continue;   // tile fully masked for this wave (uniform)

        // ---- S^T = K . Q^T  (C: col = q = l31, row = kv = crow(r,hi)) ----
        f32x16 st0, st1;
        #pragma unroll
        for (int r = 0; r < 16; ++r) { st0[r] = 0.f; st1[r] = 0.f; }
        #pragma unroll
        for (int dt = 0; dt < 4; ++dt) {
            const int ca = dt * 32 + hi * 16;
            bf16x8 k0 = *(const bf16x8*)((const char*)sK + l31 * 128 + (ca ^ ((l31 & 7) << 4)));
            bf16x8 k1 = *(const bf16x8*)((const char*)sK + (32 + l31) * 128 + (ca ^ ((l31 & 7) << 4)));
            st0 = __builtin_amdgcn_mfma_f32_32x32x16_bf16(k0, qf[dt], st0, 0, 0, 0);
            st1 = __builtin_amdgcn_mfma_f32_32x32x16_bf16(k1, qf[dt], st1, 0, 0, 0);
        }

        // ---- causal mask (diagonal region only) ----
        if (kv0 + KB - 1 > qw) {
            #pragma unroll
            for (int r = 0; r < 16; ++r) {
                const int kr = (r & 3) + 8 * (r >> 2) + 4 * hi;
                if (kv0 + kr > qr)      st0[r] = -1e30f;
                if (kv0 + 32 + kr > qr) st1[r] = -1e30f;
            }
        }

        // ---- online softmax, in-lane + one cross-half combine ----
        float pm = st0[0];
        #pragma unroll
        for (int r = 1; r < 16; ++r) pm = fmaxf(pm, st0[r]);
        #pragma unroll
        for (int r = 0; r < 16; ++r) pm = fmaxf(pm, st1[r]);
        pm = fmaxf(pm, __shfl_xor(pm, 32));

        constexpr float THR = 8.0f * 1.44269504088896340736f;   // defer-max, log2 domain
        if (!__all(pm - m_i <= THR)) {
            const float nm = fmaxf(m_i, pm);
            const float cf = exp2fast(m_i - nm);
            #pragma unroll
            for (int r = 0; r < 16; ++r) {
                const int kr = (r & 3) + 8 * (r >> 2) + 4 * hi;
                const float cfr = __shfl(cf, kr);
                o0[r] *= cfr; o1[r] *= cfr;
            }
            l_i *= cf;
            m_i = nm;
        }

        float rs = 0.f;
        #pragma unroll
        for (int r = 0; r < 16; ++r) { st0[r] = exp2fast(st0[r] - m_i); rs += st0[r]; }
        #pragma unroll
        for (int r = 0; r < 16; ++r) { st1[r] = exp2fast(st1[r] - m_i); rs += st1[r]; }
        rs += __shfl_xor(rs, 32);
        l_i += rs;

        // ---- P -> bf16 A-fragments in-register (cvt_pk + permlane32_swap) ----
        bf16x8 pf[4];
        {
            unsigned pk[8];
            #pragma unroll
            for (int i = 0; i < 8; ++i) pk[i] = cvtpk(st0[2 * i], st0[2 * i + 1]);
            #pragma unroll
            for (int c = 0; c < 2; ++c) {
                unsigned x0, y0, x1, y1;
                half_swap(pk[4 * c + 0], pk[4 * c + 2], x0, y0);
                half_swap(pk[4 * c + 1], pk[4 * c + 3], x1, y1);
                union { unsigned u[4]; bf16x8 v; } uu;
                uu.u[0] = x0; uu.u[1] = x1; uu.u[2] = y0; uu.u[3] = y1;
                pf[c] = uu.v;
            }
            #pragma unroll
            for (int i = 0; i < 8; ++i) pk[i] = cvtpk(st1[2 * i], st1[2 * i + 1]);
            #pragma unroll
            for (int c = 0; c < 2; ++c) {
                unsigned x0, y0, x1, y1;
                half_swap(pk[4 * c + 0], pk[4 * c + 2], x0, y0);
                half_swap(pk[4 * c + 1], pk[4 * c + 3], x1, y1);
                union { unsigned u[4]; bf16x8 v; } uu;
                uu.u[0] = x0; uu.u[1] = x1; uu.u[2] = y0; uu.u[3] = y1;
                pf[2 + c] = uu.v;
            }
        }

        // ---- O += P V  (C: col = d = l31 (+32), row = q = crow(r,hi)) ----
        #pragma unroll
        for (int ks = 0; ks < 4; ++ks) {
            const int cv = ks * 32 + hi * 16;
            bf16x8 v0 = *(const bf16x8*)((const char*)sV + l31 * 128 + (cv ^ ((l31 & 7) << 4)));
            o0 = __builtin_amdgcn_mfma_f32_32x32x16_bf16(pf[ks], v0, o0, 0, 0, 0);
            bf16x8 v1 = *(const bf16x8*)((const char*)sV + (32 + l31) * 128 + (cv ^ ((l31 & 7) << 4)));
            o1 = __builtin_amdgcn_mfma_f32_32x32x16_bf16(pf[ks], v1, o1, 0, 0, 0);
        }
    }

    // ---- epilogue: O / l ----
    float* Ob = Og + base;
    #pragma unroll
    for (int r = 0; r < 16; ++r) {
        const int kr  = (r & 3) + 8 * (r >> 2) + 4 * hi;
        const float ll = __shfl(l_i, kr);
        const float inv = 1.0f / ll;
        const int row = qw + kr;
        Ob[(size_t)row * DH + l31]      = o0[r] * inv;
        Ob[(size_t)row * DH + 32 + l31] = o1[r] * inv;
    }
}

extern "C" void kernel_launch(void* const* d_in, const int* in_sizes, int n_in,
                              void* d_out, int out_size, void* d_ws, size_t ws_size,
                              hipStream_t stream) {
    const float* q = (const float*)d_in[0];
    const float* k = (const float*)d_in[1];
    const float* v = (const float*)d_in[2];
    // d_in[3] is the causal tril mask — structure known, not read.
    float* out = (float*)d_out;

    short* Kb = (short*)d_ws;                          // 16 MiB bf16 K
    short* Vt = Kb + (size_t)BH * SEQ * DH;            // 16 MiB bf16 V^T

    prep_kernel<<<dim3(BH * NST), dim3(256), 0, stream>>>(k, v, Kb, Vt);
    fattn2_kernel<<<dim3(BH * NQT), dim3(512), 0, stream>>>(q, Kb, Vt, out);
}